// Round 16
// baseline (208.453 us; speedup 1.0000x reference)
//
#include <hip/hip_runtime.h>
#include <cstdint>
#include <cstddef>

#define VAR0_ 0.1f
#define VAR1_ 0.2f
#define KTOP_ 5
#define T1_ 0.35f
#define T2_ 0.5f
#define ALPHA_ 0.25f
#define BETA_ 0.11f
#define BS 256
#define BSK 128        // k_per_prior block size
#define NSPLIT 16      // row-max P splits
#define ILP 4

__device__ __forceinline__ float sl1(float d) {
    float x = fabsf(d);
    return (x >= BETA_) ? (x - 0.5f * BETA_) : (0.5f * x * x / BETA_);
}

// ---------------- K1: per-prior — MERGED single n-loop (stage-1 + stage-2 pretest) ----------------
// Round-16: one pass over truths (tr4/trA read once per n, not twice), trT
// computed in-register, stage-2 h-clamp dropped (w>=0 & thr>0 => identical mask),
// da recomputed in harvest (identical fp expression). 8 indep chains/iter.
// NOTE: #pragma unroll 2 only — full unroll at N=32 spilled (round-4).
__global__ void k_per_prior(const float4* __restrict__ loc4, const float4* __restrict__ priors4,
                            const float* __restrict__ targets,
                            float4* __restrict__ recs4,
                            float* __restrict__ cand_v, int* __restrict__ cand_i,
                            int* __restrict__ cand_cnt,
                            int P, int N, int CAP) {
    int b = blockIdx.y;
    int tid = threadIdx.x;
    int base = blockIdx.x * (BSK * ILP) + tid;
    __shared__ float4 tr4[64];
    __shared__ float trA[64];
    for (int t = tid; t < N; t += BSK) {
        float x1 = targets[(size_t)(b * N + t) * 5 + 0];
        float y1 = targets[(size_t)(b * N + t) * 5 + 1];
        float x2 = targets[(size_t)(b * N + t) * 5 + 2];
        float y2 = targets[(size_t)(b * N + t) * 5 + 3];
        tr4[t] = make_float4(x1, y1, x2, y2);
        trA[t] = (x2 - x1) * (y2 - y1);
    }
    __syncthreads();
    if (base >= P) return;

    float px1[ILP], py1[ILP], px2[ILP], py2[ILP], pa[ILP];
    float dx1[ILP], dy1[ILP], dx2[ILP], dy2[ILP], daC[ILP];
#pragma unroll
    for (int k = 0; k < ILP; k++) {
        int i = base + k * BSK;
        bool v = (i < P);
        float4 pr = v ? priors4[i] : make_float4(0.f, 0.f, 1.f, 1.f);
        float4 lc = v ? loc4[(size_t)b * P + i] : make_float4(0.f, 0.f, 0.f, 0.f);
        px1[k] = pr.x - pr.z * 0.5f; py1[k] = pr.y - pr.w * 0.5f;
        px2[k] = pr.x + pr.z * 0.5f; py2[k] = pr.y + pr.w * 0.5f;
        pa[k] = (px2[k] - px1[k]) * (py2[k] - py1[k]);
        float dcx = pr.x + lc.x * VAR0_ * pr.z;
        float dcy = pr.y + lc.y * VAR0_ * pr.w;
        float dw = pr.z * expf(lc.z * VAR1_);
        float dh = pr.w * expf(lc.w * VAR1_);
        dx1[k] = dcx - dw * 0.5f; dy1[k] = dcy - dh * 0.5f;
        dx2[k] = dcx + dw * 0.5f; dy2[k] = dcy + dh * 0.5f;
        daC[k] = ((dx2[k] - dx1[k]) * (dy2[k] - dy1[k])) * 0.33330f;
    }

    float bi[ILP], bu[ILP]; int bn[ILP];
    unsigned long long hm[ILP];
#pragma unroll
    for (int k = 0; k < ILP; k++) { bi[k] = -1.f; bu[k] = 1.f; bn[k] = 0; hm[k] = 0ull; }

#pragma unroll 2
    for (int n = 0; n < N; n++) {
        float4 t4 = tr4[n];
        float ta = trA[n];
        float tt = ta * 0.33330f;
#pragma unroll
        for (int k = 0; k < ILP; k++) {
            // stage-1: IoU(truth, prior_pt), divide-free argmax (first-max tiebreak)
            float lx = fmaxf(t4.x, px1[k]), ly = fmaxf(t4.y, py1[k]);
            float rx = fminf(t4.z, px2[k]), ry = fminf(t4.w, py2[k]);
            float w = fmaxf(rx - lx, 0.f), h = fmaxf(ry - ly, 0.f);
            float inter = w * h, uni = ta + pa[k] - inter;
            bool bet = inter * bu[k] > bi[k] * uni;
            bi[k] = bet ? inter : bi[k]; bu[k] = bet ? uni : bu[k]; bn[k] = bet ? n : bn[k];
            // stage-2 pretest (conservative): w2 clamped, h2 unclamped (h2<=0 -> inter2<=0<thr)
            float lx2 = fmaxf(t4.x, dx1[k]), ly2 = fmaxf(t4.y, dy1[k]);
            float rx2 = fminf(t4.z, dx2[k]), ry2 = fminf(t4.w, dy2[k]);
            float w2 = fmaxf(rx2 - lx2, 0.f);
            float inter2 = w2 * (ry2 - ly2);
            if (inter2 >= tt + daC[k]) hm[k] |= (1ull << n);
        }
    }

    // deferred harvest (exact both-clamped IoU + atomic) + packed store
#pragma unroll
    for (int k = 0; k < ILP; k++) {
        int i = base + k * BSK;
        if (i >= P) continue;
        float da = (dx2[k] - dx1[k]) * (dy2[k] - dy1[k]);  // identical fp expr as daC source
        int had = 0;
        unsigned long long m = hm[k];
        while (m) {
            int n = __ffsll((long long)m) - 1;
            m &= m - 1;
            float4 t4 = tr4[n];
            float lx = fmaxf(t4.x, dx1[k]), ly = fmaxf(t4.y, dy1[k]);
            float rx = fminf(t4.z, dx2[k]), ry = fminf(t4.w, dy2[k]);
            float w = fmaxf(rx - lx, 0.f), h = fmaxf(ry - ly, 0.f);
            float inter = w * h;
            float v = inter / (trA[n] + da - inter);
            if (v >= T2_) {
                had = 1;
                int pos = atomicAdd(&cand_cnt[b * N + n], 1);
                if (pos < CAP) {
                    size_t o = (size_t)(b * N + n) * CAP + pos;
                    cand_v[o] = v; cand_i[o] = i;
                }
            }
        }
        recs4[(size_t)b * P + i] =
            make_float4(bi[k] / bu[k], __int_as_float(bn[k] | (had << 16)), __int_as_float(0), 0.f);
    }
}

// ---------------- K1b: row max/argmax — 4 truths x P-chunk, 4 chains (round-10 proven) ----------------
__global__ void k_row_max_part(const float4* __restrict__ priors4, const float* __restrict__ targets,
                               float* __restrict__ part_max, int* __restrict__ part_arg,
                               int P, int N) {
    int s = blockIdx.x, b = blockIdx.y, g = blockIdx.z;
    int n0 = g * 4;
    int chunk = (P + NSPLIT - 1) / NSPLIT;
    int i0 = s * chunk;
    int i1 = min(P, i0 + chunk);
    float tx1[4], ty1[4], tx2[4], ty2[4], ta[4];
#pragma unroll
    for (int k = 0; k < 4; k++) {
        int n = min(n0 + k, N - 1);
        tx1[k] = targets[(size_t)(b * N + n) * 5 + 0];
        ty1[k] = targets[(size_t)(b * N + n) * 5 + 1];
        tx2[k] = targets[(size_t)(b * N + n) * 5 + 2];
        ty2[k] = targets[(size_t)(b * N + n) * 5 + 3];
        ta[k] = (tx2[k] - tx1[k]) * (ty2[k] - ty1[k]);
    }
    float cI[4], cU[4]; int cX[4];
#pragma unroll
    for (int k = 0; k < 4; k++) { cI[k] = -1.f; cU[k] = 1.f; cX[k] = 0x7fffffff; }
    for (int i = i0 + threadIdx.x; i < i1; i += BS) {
        float4 pr = priors4[i];
        float px1 = pr.x - pr.z * 0.5f, py1 = pr.y - pr.w * 0.5f;
        float px2 = pr.x + pr.z * 0.5f, py2 = pr.y + pr.w * 0.5f;
        float pa = (px2 - px1) * (py2 - py1);
#pragma unroll
        for (int k = 0; k < 4; k++) {
            float lx = fmaxf(tx1[k], px1), ly = fmaxf(ty1[k], py1);
            float rx = fminf(tx2[k], px2), ry = fminf(ty2[k], py2);
            float w = fmaxf(rx - lx, 0.f), h = fmaxf(ry - ly, 0.f);
            float inter = w * h;
            float uni = ta[k] + pa - inter;
            bool bet = inter * cU[k] > cI[k] * uni;  // strict >, i asc -> smallest idx
            cI[k] = bet ? inter : cI[k]; cU[k] = bet ? uni : cU[k]; cX[k] = bet ? i : cX[k];
        }
    }
    int tid = threadIdx.x;
    int lane = tid & 63, wid = tid >> 6;
    __shared__ float swv[BS / 64];
    __shared__ int swi[BS / 64];
#pragma unroll
    for (int k = 0; k < 4; k++) {
        if (n0 + k >= N) break;
        float bv = cI[k] / cU[k];   // one divide; merge on rounded values (ref semantics)
        int bx = cX[k];
#pragma unroll
        for (int off = 32; off > 0; off >>= 1) {
            float ov = __shfl_xor(bv, off);
            int oi = __shfl_xor(bx, off);
            if (ov > bv || (ov == bv && oi < bx)) { bv = ov; bx = oi; }
        }
        if (lane == 0) { swv[wid] = bv; swi[wid] = bx; }
        __syncthreads();
        if (tid == 0) {
            float fv = swv[0]; int fi = swi[0];
            for (int wv = 1; wv < BS / 64; wv++) {
                if (swv[wv] > fv || (swv[wv] == fv && swi[wv] < fi)) { fv = swv[wv]; fi = swi[wv]; }
            }
            int o = (b * N + (n0 + k)) * NSPLIT + s;
            part_max[o] = fv; part_arg[o] = fi;
        }
        __syncthreads();
    }
}

// ---------------- FAT2: topk (blocks [0,N)) ∥ greedy (block N) — round-11 proven ----------------
__global__ void k_fat2(const float4* __restrict__ loc4, const float4* __restrict__ priors4,
                       const float* __restrict__ targets,
                       const float* __restrict__ cand_v, const int* __restrict__ cand_i,
                       const int* __restrict__ cand_cnt,
                       float* __restrict__ tk_s, int* __restrict__ tk_i,
                       const float* __restrict__ part_max, const int* __restrict__ part_arg,
                       float* __restrict__ recs,
                       int P, int N, int CAP) {
    int b = blockIdx.y;
    int tid = threadIdx.x;
    if ((int)blockIdx.x < N) {
        // ===== top-5 of thresholded c_iou (lax.top_k semantics) =====
        int n = blockIdx.x;
        int row = b * N + n;
        float vals[KTOP_]; int ids[KTOP_];
#pragma unroll
        for (int k = 0; k < KTOP_; k++) { vals[k] = -1.f; ids[k] = 0x7fffffff; }
        int cnt = cand_cnt[row];
        if (cnt <= CAP) {
            for (int k = tid; k < cnt; k += blockDim.x) {
                float cv = cand_v[(size_t)row * CAP + k];
                int ci = cand_i[(size_t)row * CAP + k];
#pragma unroll
                for (int q = 0; q < KTOP_; q++) {
                    bool better = (cv > vals[q]) || ((cv == vals[q]) && (ci < ids[q]));
                    float tv = better ? cv : vals[q]; int ti = better ? ci : ids[q];
                    cv = better ? vals[q] : cv; ci = better ? ids[q] : ci;
                    vals[q] = tv; ids[q] = ti;
                }
            }
        } else {
            // deterministic fallback: full rescan (overflowed candidate buffer)
            float tx1 = targets[(size_t)row * 5 + 0], ty1 = targets[(size_t)row * 5 + 1];
            float tx2 = targets[(size_t)row * 5 + 2], ty2 = targets[(size_t)row * 5 + 3];
            float ta = (tx2 - tx1) * (ty2 - ty1);
            for (int i = tid; i < P; i += blockDim.x) {
                float4 pr = priors4[i];
                size_t bp = (size_t)b * P + i;
                float4 lc = loc4[bp];
                float dcx = pr.x + lc.x * VAR0_ * pr.z;
                float dcy = pr.y + lc.y * VAR0_ * pr.w;
                float dw = pr.z * expf(lc.z * VAR1_);
                float dh = pr.w * expf(lc.w * VAR1_);
                float dx1 = dcx - dw * 0.5f, dy1 = dcy - dh * 0.5f;
                float dx2 = dcx + dw * 0.5f, dy2 = dcy + dh * 0.5f;
                float lx = fmaxf(tx1, dx1), ly = fmaxf(ty1, dy1);
                float rx = fminf(tx2, dx2), ry = fminf(ty2, dy2);
                float w = fmaxf(rx - lx, 0.f), h = fmaxf(ry - ly, 0.f);
                float inter = w * h;
                float uni = ta + (dx2 - dx1) * (dy2 - dy1) - inter;
                if (inter >= uni * 0.4999990f) {
                    float v = inter / uni;
                    if (v >= T2_) {
                        float cv = v; int ci = i;
#pragma unroll
                        for (int q = 0; q < KTOP_; q++) {
                            bool better = (cv > vals[q]) || ((cv == vals[q]) && (ci < ids[q]));
                            float tv = better ? cv : vals[q]; int ti = better ? ci : ids[q];
                            cv = better ? vals[q] : cv; ci = better ? ids[q] : ci;
                            vals[q] = tv; ids[q] = ti;
                        }
                    }
                }
            }
        }
        __shared__ float mv[BS * KTOP_];
        __shared__ int mi[BS * KTOP_];
#pragma unroll
        for (int k = 0; k < KTOP_; k++) { mv[tid * KTOP_ + k] = vals[k]; mi[tid * KTOP_ + k] = ids[k]; }
        __syncthreads();
        for (int s = BS / 2; s > 0; s >>= 1) {
            if (tid < s) {
#pragma unroll
                for (int j = 0; j < KTOP_; j++) {
                    float cv = mv[(tid + s) * KTOP_ + j];
                    int ci = mi[(tid + s) * KTOP_ + j];
#pragma unroll
                    for (int q = 0; q < KTOP_; q++) {
                        bool better = (cv > vals[q]) || ((cv == vals[q]) && (ci < ids[q]));
                        float tv = better ? cv : vals[q]; int ti = better ? ci : ids[q];
                        cv = better ? vals[q] : cv; ci = better ? ids[q] : ci;
                        vals[q] = tv; ids[q] = ti;
                    }
                }
#pragma unroll
                for (int k = 0; k < KTOP_; k++) { mv[tid * KTOP_ + k] = vals[k]; mi[tid * KTOP_ + k] = ids[k]; }
            }
            __syncthreads();
        }
        if (tid == 0) {
#pragma unroll
            for (int k = 0; k < KTOP_; k++) {
                tk_s[(size_t)row * KTOP_ + k] = (vals[k] > 0.f) ? vals[k] : 0.f;
                tk_i[(size_t)row * KTOP_ + k] = (ids[k] == 0x7fffffff) ? 0 : ids[k];
            }
        }
    } else {
        // ===== greedy bipartite matching: wave 0 works, waves 1-3 mirror barriers =====
        int lane = tid & 63, wid = tid >> 6;
        extern __shared__ unsigned int mask[];
        int maskWords = (P + 31) >> 5;
        for (int w = tid; w < maskWords; w += BS) mask[w] = 0u;

        float rmax = -2.f; int rarg = 0x7fffffff; int alive = 0;
        float tx1 = 0.f, ty1 = 0.f, tx2 = 0.f, ty2 = 0.f, ta = 0.f;
        if (wid == 0 && lane < N) {
            float bv = -2.f; int bi = 0x7fffffff;
            for (int s = 0; s < NSPLIT; s++) {
                int o = (b * N + lane) * NSPLIT + s;
                float v = part_max[o]; int ix = part_arg[o];
                if (v > bv || (v == bv && ix < bi)) { bv = v; bi = ix; }
            }
            rmax = bv; rarg = bi;
            alive = 1;
            tx1 = targets[(size_t)(b * N + lane) * 5 + 0];
            ty1 = targets[(size_t)(b * N + lane) * 5 + 1];
            tx2 = targets[(size_t)(b * N + lane) * 5 + 2];
            ty2 = targets[(size_t)(b * N + lane) * 5 + 3];
            ta = (tx2 - tx1) * (ty2 - ty1);
        }
        __syncthreads();

        for (int it = 0; it < N; it++) {
            int sel = 0;
            if (wid == 0) {
                float v = (lane < N && alive) ? rmax : -3.f;
                int idx = lane;
#pragma unroll
                for (int off = 32; off > 0; off >>= 1) {
                    float ov = __shfl_xor(v, off);
                    int oi = __shfl_xor(idx, off);
                    if (ov > v || (ov == v && oi < idx)) { v = ov; idx = oi; }
                }
                int bj = idx;
                float bv = v;
                sel = __shfl(rarg, bj);
                if (lane == bj) alive = 0;
                if (lane == 0) {
                    float* base = recs + 4 * ((size_t)b * P + sel);
                    int wrd = __float_as_int(base[1]);
                    base[0] = bv;
                    base[1] = __int_as_float((wrd & ~0xFFFF) | bj);  // preserve hadCand bit 16
                    mask[sel >> 5] |= (1u << (sel & 31));
                }
            }
            __syncthreads();
            if (wid == 0) {
                unsigned long long coll = __ballot(lane < N && alive && rarg == sel);
                while (coll) {
                    int r = __ffsll((long long)coll) - 1;
                    coll &= coll - 1;
                    float rx1 = __shfl(tx1, r), ry1 = __shfl(ty1, r);
                    float rx2 = __shfl(tx2, r), ry2 = __shfl(ty2, r);
                    float ra = __shfl(ta, r);
                    float n_i = -2.f, n_u = 1.f; int ni = 0x7fffffff;
                    for (int i = lane; i < P; i += 64) {
                        if (mask[i >> 5] & (1u << (i & 31))) continue;
                        float4 pr = priors4[i];
                        float px1 = pr.x - pr.z * 0.5f, py1 = pr.y - pr.w * 0.5f;
                        float px2 = pr.x + pr.z * 0.5f, py2 = pr.y + pr.w * 0.5f;
                        float lx = fmaxf(rx1, px1), ly = fmaxf(ry1, py1);
                        float rx = fminf(rx2, px2), ry = fminf(ry2, py2);
                        float w = fmaxf(rx - lx, 0.f), h = fmaxf(ry - ly, 0.f);
                        float inter = w * h;
                        float uni = ra + (px2 - px1) * (py2 - py1) - inter;
                        bool better = inter * n_u > n_i * uni;
                        n_i = better ? inter : n_i; n_u = better ? uni : n_u; ni = better ? i : ni;
                    }
                    float nv = n_i / n_u;
#pragma unroll
                    for (int off = 32; off > 0; off >>= 1) {
                        float ov = __shfl_xor(nv, off);
                        int oi = __shfl_xor(ni, off);
                        if (ov > nv || (ov == nv && oi < ni)) { nv = ov; ni = oi; }
                    }
                    if (lane == r) { rmax = nv; rarg = ni; }
                }
            }
            __syncthreads();
        }
    }
}

// ---------------- K3b: assign loop, parallel last-writer-wins ----------------
__global__ void k_assign(const float* __restrict__ targets,
                         const float* __restrict__ tk_s, const int* __restrict__ tk_i,
                         float* __restrict__ recs, int P, int N) {
    int b = blockIdx.x;
    int tid = threadIdx.x;
    int T = N * KTOP_;  // 160
    __shared__ int sh_p[512];
    __shared__ float sh_s[512];
    __shared__ int sh_c[512];
    if (tid < T) {
        int i = tid / KTOP_, j = tid % KTOP_;
        int p = tk_i[(size_t)(b * N + i) * KTOP_ + j];
        float s = tk_s[(size_t)(b * N + i) * KTOP_ + j];
        const float* base = recs + 4 * ((size_t)b * P + p);
        float bs = base[0];
        int bj = __float_as_int(base[1]) & 0xFFFF;
        float conf1 = (bs < T1_) ? 0.f : targets[(size_t)(b * N + bj) * 5 + 4];
        sh_p[tid] = p; sh_s[tid] = s;
        sh_c[tid] = (conf1 < 1.f && s > 0.f) ? 1 : 0;
    }
    __syncthreads();
    if (tid < T && sh_c[tid]) {
        int p = sh_p[tid];
        bool last = true;
        for (int t2 = tid + 1; t2 < T; t2++) {
            if (sh_c[t2] && sh_p[t2] == p) { last = false; break; }
        }
        if (last) {
            float* base = recs + 4 * ((size_t)b * P + p);
            base[2] = __int_as_float(tid / KTOP_);
            base[3] = sh_s[tid];
        }
    }
}

// ---------------- K4: per-element losses + block partial sums (round-10 proven) ----------------
__global__ void k_loss(const float4* __restrict__ loc4, const float* __restrict__ conf,
                       const float4* __restrict__ priors4, const float* __restrict__ targets,
                       const float4* __restrict__ recs4,
                       double* __restrict__ partials,
                       int P, int N, int C) {
    int b = blockIdx.y;
    int i = blockIdx.x * blockDim.x + threadIdx.x;
    double l1 = 0.0, l2 = 0.0, f1 = 0.0, f2 = 0.0;
    int n1 = 0, n2 = 0;
    if (i < P) {
        size_t bp = (size_t)b * P + i;
        float4 r = recs4[bp];             // one 16B load: {bt_score, btcb, cb_idx2, c_score}
        float bs = r.x;
        int widx = __float_as_int(r.y);
        int bj = widx & 0xFFFF;
        int hadCand = (widx >> 16) & 1;   // == (c_bp_score >= T2)
        float cs = r.w;
        int cj = (cs > 0.f) ? __float_as_int(r.z) : 0;
        float lab1 = targets[(size_t)(b * N + bj) * 5 + 4];
        float conf1 = (bs < T1_) ? 0.f : lab1;
        if ((bs < T1_) && hadCand && (cs < T2_)) conf1 = -1.f;
        float lab2 = targets[(size_t)(b * N + cj) * 5 + 4];
        float conf2 = (cs < T2_) ? -1.f : lab2;
        bool m1 = conf1 > 0.f, m2 = conf2 > 0.f;
        n1 = m1 ? 1 : 0; n2 = m2 ? 1 : 0;

        if (m1 || m2) {   // loc/priors only needed for smooth-l1 of matched priors (~2%)
            float4 pr = priors4[i];
            float pcx = pr.x, pcy = pr.y, pw = pr.z, ph = pr.w;
            float4 lc = loc4[bp];
            float p0 = lc.x, p1 = lc.y, p2 = lc.z, p3 = lc.w;
            if (m1) {
                const float* tb = &targets[(size_t)(b * N + bj) * 5];
                float gx = ((tb[0] + tb[2]) * 0.5f - pcx) / (VAR0_ * pw);
                float gy = ((tb[1] + tb[3]) * 0.5f - pcy) / (VAR0_ * ph);
                float gw = logf((tb[2] - tb[0]) / pw) / VAR1_;
                float gh = logf((tb[3] - tb[1]) / ph) / VAR1_;
                l1 = (double)(sl1(p0 - gx) + sl1(p1 - gy) + sl1(p2 - gw) + sl1(p3 - gh));
            }
            if (m2) {
                const float* tb = &targets[(size_t)(b * N + cj) * 5];
                float gx = ((tb[0] + tb[2]) * 0.5f - pcx) / (VAR0_ * pw);
                float gy = ((tb[1] + tb[3]) * 0.5f - pcy) / (VAR0_ * ph);
                float gw = logf((tb[2] - tb[0]) / pw) / VAR1_;
                float gh = logf((tb[3] - tb[1]) / ph) / VAR1_;
                l2 = (double)(sl1(p0 - gx) + sl1(p1 - gy) + sl1(p2 - gw) + sl1(p3 - gh));
            }
        }
        float x0, x1v;
        if (C == 2) {
            float2 cv2 = ((const float2*)conf)[bp];
            x0 = cv2.x; x1v = cv2.y;
        } else {
            x0 = conf[bp * C + 0]; x1v = conf[bp * C + 1];
        }
        {   // focal 1
            float t = fmaxf(conf1, 0.f);
            float keep = (conf1 >= 0.f) ? 1.f : 0.f;
            float x = (t >= 1.f) ? x1v : x0;
            float ce = fmaxf(x, 0.f) - x * t + log1pf(expf(-fabsf(x)));
            float a = t * ALPHA_ + (1.f - t) * (1.f - ALPHA_);
            float pr_ = 1.f / (1.f + expf(-x));
            float pt = (t == 1.f) ? pr_ : (1.f - pr_);
            float om = 1.f - pt;
            f1 = (double)(a * om * om * ce * keep);
        }
        {   // focal 2 (iou-weighted)
            float t = fmaxf(conf2, 0.f);
            float keep = (conf2 >= 0.f) ? 1.f : 0.f;
            float x = (t >= 1.f) ? x1v : x0;
            float ce = fmaxf(x, 0.f) - x * t + log1pf(expf(-fabsf(x)));
            float a = cs * (t * ALPHA_ + (1.f - t) * (1.f - ALPHA_));
            float pr_ = 1.f / (1.f + expf(-x));
            float pt = (t == 1.f) ? pr_ : (1.f - pr_);
            float om = 1.f - pt;
            f2 = (double)(a * om * om * ce * keep);
        }
    }
    int tid = threadIdx.x;
    int lane = tid & 63, wid = tid >> 6;
#pragma unroll
    for (int off = 32; off > 0; off >>= 1) {
        l1 += __shfl_xor(l1, off);
        l2 += __shfl_xor(l2, off);
        f1 += __shfl_xor(f1, off);
        f2 += __shfl_xor(f2, off);
        n1 += __shfl_xor(n1, off);
        n2 += __shfl_xor(n2, off);
    }
    __shared__ double swd[BS / 64][4];
    __shared__ int swn[BS / 64][2];
    if (lane == 0) {
        swd[wid][0] = l1; swd[wid][1] = l2; swd[wid][2] = f1; swd[wid][3] = f2;
        swn[wid][0] = n1; swn[wid][1] = n2;
    }
    __syncthreads();
    if (tid == 0) {
        double a0 = 0, a1 = 0, a2 = 0, a3 = 0; int b0 = 0, b1 = 0;
        for (int wv = 0; wv < BS / 64; wv++) {
            a0 += swd[wv][0]; a1 += swd[wv][1]; a2 += swd[wv][2]; a3 += swd[wv][3];
            b0 += swn[wv][0]; b1 += swn[wv][1];
        }
        int blk = blockIdx.y * gridDim.x + blockIdx.x;
        partials[(size_t)blk * 6 + 0] = a0;
        partials[(size_t)blk * 6 + 1] = a1;
        partials[(size_t)blk * 6 + 2] = a2;
        partials[(size_t)blk * 6 + 3] = a3;
        partials[(size_t)blk * 6 + 4] = (double)b0;
        partials[(size_t)blk * 6 + 5] = (double)b1;
    }
}

// ---------------- K5: final reduction + loss assembly (round-10 proven) ----------------
__global__ void k_final(const double* __restrict__ partials, int nPart, float* __restrict__ out) {
    int tid = threadIdx.x;
    double a[6] = {0, 0, 0, 0, 0, 0};
    for (int k = tid; k < nPart; k += BS) {
#pragma unroll
        for (int j = 0; j < 6; j++) a[j] += partials[(size_t)k * 6 + j];
    }
    __shared__ double sd[BS * 6];
#pragma unroll
    for (int j = 0; j < 6; j++) sd[tid * 6 + j] = a[j];
    __syncthreads();
    for (int s = BS / 2; s > 0; s >>= 1) {
        if (tid < s) {
#pragma unroll
            for (int j = 0; j < 6; j++) sd[tid * 6 + j] += sd[(tid + s) * 6 + j];
        }
        __syncthreads();
    }
    if (tid == 0) {
        double L1 = sd[0], L2 = sd[1], F1 = sd[2], F2 = sd[3], N1 = sd[4], N2 = sd[5];
        double l1v = L1 / fmax(N1, 1.0), l2v = L2 / fmax(N2, 1.0);
        double f1v = F1 / fmax(N1, 1.0), f2v = F2 / fmax(N2, 1.0);
        double locl = (N1 > 0 ? l1v : 0.0) + (N2 > 0 ? l2v : 0.0);
        double clsl = (N1 > 0 ? f1v : 0.0) + (N2 > 0 ? f2v : 0.0);
        if (N1 == 0 && N2 == 0) { locl = 1e-4; clsl = 1e-4; }
        out[0] = (float)locl;
        out[1] = (float)clsl;
    }
}

extern "C" void kernel_launch(void* const* d_in, const int* in_sizes, int n_in,
                              void* d_out, int out_size, void* d_ws, size_t ws_size,
                              hipStream_t stream) {
    const float* targets = (const float*)d_in[3];
    const float* conf = (const float*)d_in[1];
    const float4* loc4 = (const float4*)d_in[0];
    const float4* priors4 = (const float4*)d_in[2];

    int P = in_sizes[2] / 4;
    int B = in_sizes[0] / (P * 4);
    int N = in_sizes[3] / (B * 5);
    int C = in_sizes[1] / (B * P);
    const int CAP = 2048;
    size_t BP = (size_t)B * P;

    unsigned char* ws = (unsigned char*)d_ws;
    size_t off = 0;
    auto alloc = [&](size_t bytes) { size_t cur = off; off += (bytes + 255) & ~(size_t)255; return cur; };
    float* recs = (float*)(ws + alloc(BP * 16));      // packed {bt_score, btcb, cb_idx2, c_score}
    float* part_max = (float*)(ws + alloc((size_t)B * N * NSPLIT * 4));
    int* part_arg = (int*)(ws + alloc((size_t)B * N * NSPLIT * 4));
    float* tk_s = (float*)(ws + alloc((size_t)B * N * KTOP_ * 4));
    int* tk_i = (int*)(ws + alloc((size_t)B * N * KTOP_ * 4));
    float* cand_v = (float*)(ws + alloc((size_t)B * N * CAP * 4));
    int* cand_i = (int*)(ws + alloc((size_t)B * N * CAP * 4));
    int* cand_cnt = (int*)(ws + alloc((size_t)B * N * 4));
    int bx = (P + BS - 1) / BS;
    double* partials = (double*)(ws + alloc((size_t)bx * B * 6 * 8));
    float* out = (float*)d_out;

    hipMemsetAsync(cand_cnt, 0, (size_t)B * N * 4, stream);

    int bx4 = (P + BSK * ILP - 1) / (BSK * ILP);
    k_per_prior<<<dim3(bx4, B), BSK, 0, stream>>>(loc4, priors4, targets, (float4*)recs,
                                                  cand_v, cand_i, cand_cnt, P, N, CAP);
    int ngroup = (N + 3) / 4;
    k_row_max_part<<<dim3(NSPLIT, B, ngroup), BS, 0, stream>>>(priors4, targets,
                                                               part_max, part_arg, P, N);
    int maskWords = (P + 31) / 32;
    size_t shmem = (size_t)maskWords * 4;
    k_fat2<<<dim3(N + 1, B), BS, shmem, stream>>>(loc4, priors4, targets,
                                                  cand_v, cand_i, cand_cnt, tk_s, tk_i,
                                                  part_max, part_arg, recs, P, N, CAP);
    k_assign<<<dim3(B), BS, 0, stream>>>(targets, tk_s, tk_i, recs, P, N);
    k_loss<<<dim3(bx, B), BS, 0, stream>>>(loc4, conf, priors4, targets, (const float4*)recs,
                                           partials, P, N, C);
    k_final<<<1, BS, 0, stream>>>(partials, bx * B, out);
}

// Round 17
// 199.468 us; speedup vs baseline: 1.0450x; 1.0450x over previous
//
#include <hip/hip_runtime.h>
#include <cstdint>
#include <cstddef>

#define VAR0_ 0.1f
#define VAR1_ 0.2f
#define KTOP_ 5
#define T1_ 0.35f
#define T2_ 0.5f
#define ALPHA_ 0.25f
#define BETA_ 0.11f
#define BS 256
#define BSK 128        // k_per_prior block size
#define NSPLIT 16      // row-max P splits
#define ILP 4

__device__ __forceinline__ float sl1(float d) {
    float x = fabsf(d);
    return (x >= BETA_) ? (x - 0.5f * BETA_) : (0.5f * x * x / BETA_);
}

// ---------------- K1: per-prior stage-1 argmax + deferred harvest (round-10/15 proven) ----------------
// Two-phase structure is deliberate: merging phases (round-16) pushed VGPR 40->64,
// occupancy 42->30%, +7us. Full unroll (round-4) spilled. Keep as-is.
__global__ void k_per_prior(const float4* __restrict__ loc4, const float4* __restrict__ priors4,
                            const float* __restrict__ targets,
                            float4* __restrict__ recs4,
                            float* __restrict__ cand_v, int* __restrict__ cand_i,
                            int* __restrict__ cand_cnt,
                            int P, int N, int CAP) {
    int b = blockIdx.y;
    int tid = threadIdx.x;
    int base = blockIdx.x * (BSK * ILP) + tid;
    __shared__ float4 tr4[64];
    __shared__ float trA[64];
    __shared__ float trT[64];   // trA * 0.33330f
    for (int t = tid; t < N; t += BSK) {
        float x1 = targets[(size_t)(b * N + t) * 5 + 0];
        float y1 = targets[(size_t)(b * N + t) * 5 + 1];
        float x2 = targets[(size_t)(b * N + t) * 5 + 2];
        float y2 = targets[(size_t)(b * N + t) * 5 + 3];
        tr4[t] = make_float4(x1, y1, x2, y2);
        float a = (x2 - x1) * (y2 - y1);
        trA[t] = a;
        trT[t] = a * 0.33330f;
    }
    __syncthreads();
    if (base >= P) return;

    int iv[ILP]; int val[ILP];
    float px1[ILP], py1[ILP], px2[ILP], py2[ILP], pa[ILP];
#pragma unroll
    for (int k = 0; k < ILP; k++) {
        int i = base + k * BSK; iv[k] = i; val[k] = (i < P);
        float4 pr = val[k] ? priors4[i] : make_float4(0.f, 0.f, 1.f, 1.f);
        px1[k] = pr.x - pr.z * 0.5f; py1[k] = pr.y - pr.w * 0.5f;
        px2[k] = pr.x + pr.z * 0.5f; py2[k] = pr.y + pr.w * 0.5f;
        pa[k] = (px2[k] - px1[k]) * (py2[k] - py1[k]);
    }

    float bi[ILP], bu[ILP]; int bn[ILP];
#pragma unroll
    for (int k = 0; k < ILP; k++) { bi[k] = -1.f; bu[k] = 1.f; bn[k] = 0; }
#pragma unroll 2
    for (int n = 0; n < N; n++) {
        float4 t4 = tr4[n];
        float ta = trA[n];
#pragma unroll
        for (int k = 0; k < ILP; k++) {
            float lx = fmaxf(t4.x, px1[k]), ly = fmaxf(t4.y, py1[k]);
            float rx = fminf(t4.z, px2[k]), ry = fminf(t4.w, py2[k]);
            float w = fmaxf(rx - lx, 0.f), h = fmaxf(ry - ly, 0.f);
            float inter = w * h, uni = ta + pa[k] - inter;
            bool bet = inter * bu[k] > bi[k] * uni;
            bi[k] = bet ? inter : bi[k]; bu[k] = bet ? uni : bu[k]; bn[k] = bet ? n : bn[k];
        }
    }
    float bv[ILP];
#pragma unroll
    for (int k = 0; k < ILP; k++) bv[k] = bi[k] / bu[k];

    float dx1[ILP], dy1[ILP], dx2[ILP], dy2[ILP], da[ILP], daC[ILP];
#pragma unroll
    for (int k = 0; k < ILP; k++) {
        float4 pr = val[k] ? priors4[iv[k]] : make_float4(0.f, 0.f, 1.f, 1.f);
        float4 lc = val[k] ? loc4[(size_t)b * P + iv[k]] : make_float4(0.f, 0.f, 0.f, 0.f);
        float dcx = pr.x + lc.x * VAR0_ * pr.z;
        float dcy = pr.y + lc.y * VAR0_ * pr.w;
        float dw = pr.z * expf(lc.z * VAR1_);
        float dh = pr.w * expf(lc.w * VAR1_);
        dx1[k] = dcx - dw * 0.5f; dy1[k] = dcy - dh * 0.5f;
        dx2[k] = dcx + dw * 0.5f; dy2[k] = dcy + dh * 0.5f;
        da[k] = (dx2[k] - dx1[k]) * (dy2[k] - dy1[k]);
        daC[k] = da[k] * 0.33330f;
    }
    unsigned long long hm[ILP];
#pragma unroll
    for (int k = 0; k < ILP; k++) hm[k] = 0ull;
#pragma unroll 2
    for (int n = 0; n < N; n++) {
        float4 t4 = tr4[n];
        float tt = trT[n];
#pragma unroll
        for (int k = 0; k < ILP; k++) {
            float lx = fmaxf(t4.x, dx1[k]), ly = fmaxf(t4.y, dy1[k]);
            float rx = fminf(t4.z, dx2[k]), ry = fminf(t4.w, dy2[k]);
            float w = fmaxf(rx - lx, 0.f), h = fmaxf(ry - ly, 0.f);
            float inter = w * h;
            if (inter >= tt + daC[k]) hm[k] |= (1ull << n);
        }
    }
#pragma unroll
    for (int k = 0; k < ILP; k++) {
        if (!val[k]) continue;
        int had = 0;
        unsigned long long m = hm[k];
        while (m) {
            int n = __ffsll((long long)m) - 1;
            m &= m - 1;
            float4 t4 = tr4[n];
            float lx = fmaxf(t4.x, dx1[k]), ly = fmaxf(t4.y, dy1[k]);
            float rx = fminf(t4.z, dx2[k]), ry = fminf(t4.w, dy2[k]);
            float w = fmaxf(rx - lx, 0.f), h = fmaxf(ry - ly, 0.f);
            float inter = w * h;
            float v = inter / (trA[n] + da[k] - inter);
            if (v >= T2_) {
                had = 1;
                int pos = atomicAdd(&cand_cnt[b * N + n], 1);
                if (pos < CAP) {
                    size_t o = (size_t)(b * N + n) * CAP + pos;
                    cand_v[o] = v; cand_i[o] = iv[k];
                }
            }
        }
        recs4[(size_t)b * P + iv[k]] =
            make_float4(bv[k], __int_as_float(bn[k] | (had << 16)), __int_as_float(0), 0.f);
    }
}

// ---------------- K1b: row max/argmax — 4 truths x P-chunk, 4 chains (round-10 proven) ----------------
__global__ void k_row_max_part(const float4* __restrict__ priors4, const float* __restrict__ targets,
                               float* __restrict__ part_max, int* __restrict__ part_arg,
                               int P, int N) {
    int s = blockIdx.x, b = blockIdx.y, g = blockIdx.z;
    int n0 = g * 4;
    int chunk = (P + NSPLIT - 1) / NSPLIT;
    int i0 = s * chunk;
    int i1 = min(P, i0 + chunk);
    float tx1[4], ty1[4], tx2[4], ty2[4], ta[4];
#pragma unroll
    for (int k = 0; k < 4; k++) {
        int n = min(n0 + k, N - 1);
        tx1[k] = targets[(size_t)(b * N + n) * 5 + 0];
        ty1[k] = targets[(size_t)(b * N + n) * 5 + 1];
        tx2[k] = targets[(size_t)(b * N + n) * 5 + 2];
        ty2[k] = targets[(size_t)(b * N + n) * 5 + 3];
        ta[k] = (tx2[k] - tx1[k]) * (ty2[k] - ty1[k]);
    }
    float cI[4], cU[4]; int cX[4];
#pragma unroll
    for (int k = 0; k < 4; k++) { cI[k] = -1.f; cU[k] = 1.f; cX[k] = 0x7fffffff; }
    for (int i = i0 + threadIdx.x; i < i1; i += BS) {
        float4 pr = priors4[i];
        float px1 = pr.x - pr.z * 0.5f, py1 = pr.y - pr.w * 0.5f;
        float px2 = pr.x + pr.z * 0.5f, py2 = pr.y + pr.w * 0.5f;
        float pa = (px2 - px1) * (py2 - py1);
#pragma unroll
        for (int k = 0; k < 4; k++) {
            float lx = fmaxf(tx1[k], px1), ly = fmaxf(ty1[k], py1);
            float rx = fminf(tx2[k], px2), ry = fminf(ty2[k], py2);
            float w = fmaxf(rx - lx, 0.f), h = fmaxf(ry - ly, 0.f);
            float inter = w * h;
            float uni = ta[k] + pa - inter;
            bool bet = inter * cU[k] > cI[k] * uni;  // strict >, i asc -> smallest idx
            cI[k] = bet ? inter : cI[k]; cU[k] = bet ? uni : cU[k]; cX[k] = bet ? i : cX[k];
        }
    }
    int tid = threadIdx.x;
    int lane = tid & 63, wid = tid >> 6;
    __shared__ float swv[BS / 64];
    __shared__ int swi[BS / 64];
#pragma unroll
    for (int k = 0; k < 4; k++) {
        if (n0 + k >= N) break;
        float bv = cI[k] / cU[k];   // one divide; merge on rounded values (ref semantics)
        int bx = cX[k];
#pragma unroll
        for (int off = 32; off > 0; off >>= 1) {
            float ov = __shfl_xor(bv, off);
            int oi = __shfl_xor(bx, off);
            if (ov > bv || (ov == bv && oi < bx)) { bv = ov; bx = oi; }
        }
        if (lane == 0) { swv[wid] = bv; swi[wid] = bx; }
        __syncthreads();
        if (tid == 0) {
            float fv = swv[0]; int fi = swi[0];
            for (int wv = 1; wv < BS / 64; wv++) {
                if (swv[wv] > fv || (swv[wv] == fv && swi[wv] < fi)) { fv = swv[wv]; fi = swi[wv]; }
            }
            int o = (b * N + (n0 + k)) * NSPLIT + s;
            part_max[o] = fv; part_arg[o] = fi;
        }
        __syncthreads();
    }
}

// ---------------- FAT2: topk (blocks [0,N)) ∥ greedy (block N) — round-11 proven ----------------
__global__ void k_fat2(const float4* __restrict__ loc4, const float4* __restrict__ priors4,
                       const float* __restrict__ targets,
                       const float* __restrict__ cand_v, const int* __restrict__ cand_i,
                       const int* __restrict__ cand_cnt,
                       float* __restrict__ tk_s, int* __restrict__ tk_i,
                       const float* __restrict__ part_max, const int* __restrict__ part_arg,
                       float* __restrict__ recs,
                       int P, int N, int CAP) {
    int b = blockIdx.y;
    int tid = threadIdx.x;
    if ((int)blockIdx.x < N) {
        // ===== top-5 of thresholded c_iou (lax.top_k semantics) =====
        int n = blockIdx.x;
        int row = b * N + n;
        float vals[KTOP_]; int ids[KTOP_];
#pragma unroll
        for (int k = 0; k < KTOP_; k++) { vals[k] = -1.f; ids[k] = 0x7fffffff; }
        int cnt = cand_cnt[row];
        if (cnt <= CAP) {
            for (int k = tid; k < cnt; k += blockDim.x) {
                float cv = cand_v[(size_t)row * CAP + k];
                int ci = cand_i[(size_t)row * CAP + k];
#pragma unroll
                for (int q = 0; q < KTOP_; q++) {
                    bool better = (cv > vals[q]) || ((cv == vals[q]) && (ci < ids[q]));
                    float tv = better ? cv : vals[q]; int ti = better ? ci : ids[q];
                    cv = better ? vals[q] : cv; ci = better ? ids[q] : ci;
                    vals[q] = tv; ids[q] = ti;
                }
            }
        } else {
            // deterministic fallback: full rescan (overflowed candidate buffer)
            float tx1 = targets[(size_t)row * 5 + 0], ty1 = targets[(size_t)row * 5 + 1];
            float tx2 = targets[(size_t)row * 5 + 2], ty2 = targets[(size_t)row * 5 + 3];
            float ta = (tx2 - tx1) * (ty2 - ty1);
            for (int i = tid; i < P; i += blockDim.x) {
                float4 pr = priors4[i];
                size_t bp = (size_t)b * P + i;
                float4 lc = loc4[bp];
                float dcx = pr.x + lc.x * VAR0_ * pr.z;
                float dcy = pr.y + lc.y * VAR0_ * pr.w;
                float dw = pr.z * expf(lc.z * VAR1_);
                float dh = pr.w * expf(lc.w * VAR1_);
                float dx1 = dcx - dw * 0.5f, dy1 = dcy - dh * 0.5f;
                float dx2 = dcx + dw * 0.5f, dy2 = dcy + dh * 0.5f;
                float lx = fmaxf(tx1, dx1), ly = fmaxf(ty1, dy1);
                float rx = fminf(tx2, dx2), ry = fminf(ty2, dy2);
                float w = fmaxf(rx - lx, 0.f), h = fmaxf(ry - ly, 0.f);
                float inter = w * h;
                float uni = ta + (dx2 - dx1) * (dy2 - dy1) - inter;
                if (inter >= uni * 0.4999990f) {
                    float v = inter / uni;
                    if (v >= T2_) {
                        float cv = v; int ci = i;
#pragma unroll
                        for (int q = 0; q < KTOP_; q++) {
                            bool better = (cv > vals[q]) || ((cv == vals[q]) && (ci < ids[q]));
                            float tv = better ? cv : vals[q]; int ti = better ? ci : ids[q];
                            cv = better ? vals[q] : cv; ci = better ? ids[q] : ci;
                            vals[q] = tv; ids[q] = ti;
                        }
                    }
                }
            }
        }
        __shared__ float mv[BS * KTOP_];
        __shared__ int mi[BS * KTOP_];
#pragma unroll
        for (int k = 0; k < KTOP_; k++) { mv[tid * KTOP_ + k] = vals[k]; mi[tid * KTOP_ + k] = ids[k]; }
        __syncthreads();
        for (int s = BS / 2; s > 0; s >>= 1) {
            if (tid < s) {
#pragma unroll
                for (int j = 0; j < KTOP_; j++) {
                    float cv = mv[(tid + s) * KTOP_ + j];
                    int ci = mi[(tid + s) * KTOP_ + j];
#pragma unroll
                    for (int q = 0; q < KTOP_; q++) {
                        bool better = (cv > vals[q]) || ((cv == vals[q]) && (ci < ids[q]));
                        float tv = better ? cv : vals[q]; int ti = better ? ci : ids[q];
                        cv = better ? vals[q] : cv; ci = better ? ids[q] : ci;
                        vals[q] = tv; ids[q] = ti;
                    }
                }
#pragma unroll
                for (int k = 0; k < KTOP_; k++) { mv[tid * KTOP_ + k] = vals[k]; mi[tid * KTOP_ + k] = ids[k]; }
            }
            __syncthreads();
        }
        if (tid == 0) {
#pragma unroll
            for (int k = 0; k < KTOP_; k++) {
                tk_s[(size_t)row * KTOP_ + k] = (vals[k] > 0.f) ? vals[k] : 0.f;
                tk_i[(size_t)row * KTOP_ + k] = (ids[k] == 0x7fffffff) ? 0 : ids[k];
            }
        }
    } else {
        // ===== greedy bipartite matching: wave 0 works, waves 1-3 mirror barriers =====
        int lane = tid & 63, wid = tid >> 6;
        extern __shared__ unsigned int mask[];
        int maskWords = (P + 31) >> 5;
        for (int w = tid; w < maskWords; w += BS) mask[w] = 0u;

        float rmax = -2.f; int rarg = 0x7fffffff; int alive = 0;
        float tx1 = 0.f, ty1 = 0.f, tx2 = 0.f, ty2 = 0.f, ta = 0.f;
        if (wid == 0 && lane < N) {
            float bv = -2.f; int bi = 0x7fffffff;
            for (int s = 0; s < NSPLIT; s++) {
                int o = (b * N + lane) * NSPLIT + s;
                float v = part_max[o]; int ix = part_arg[o];
                if (v > bv || (v == bv && ix < bi)) { bv = v; bi = ix; }
            }
            rmax = bv; rarg = bi;
            alive = 1;
            tx1 = targets[(size_t)(b * N + lane) * 5 + 0];
            ty1 = targets[(size_t)(b * N + lane) * 5 + 1];
            tx2 = targets[(size_t)(b * N + lane) * 5 + 2];
            ty2 = targets[(size_t)(b * N + lane) * 5 + 3];
            ta = (tx2 - tx1) * (ty2 - ty1);
        }
        __syncthreads();

        for (int it = 0; it < N; it++) {
            int sel = 0;
            if (wid == 0) {
                float v = (lane < N && alive) ? rmax : -3.f;
                int idx = lane;
#pragma unroll
                for (int off = 32; off > 0; off >>= 1) {
                    float ov = __shfl_xor(v, off);
                    int oi = __shfl_xor(idx, off);
                    if (ov > v || (ov == v && oi < idx)) { v = ov; idx = oi; }
                }
                int bj = idx;
                float bv = v;
                sel = __shfl(rarg, bj);
                if (lane == bj) alive = 0;
                if (lane == 0) {
                    float* base = recs + 4 * ((size_t)b * P + sel);
                    int wrd = __float_as_int(base[1]);
                    base[0] = bv;
                    base[1] = __int_as_float((wrd & ~0xFFFF) | bj);  // preserve hadCand bit 16
                    mask[sel >> 5] |= (1u << (sel & 31));
                }
            }
            __syncthreads();
            if (wid == 0) {
                unsigned long long coll = __ballot(lane < N && alive && rarg == sel);
                while (coll) {
                    int r = __ffsll((long long)coll) - 1;
                    coll &= coll - 1;
                    float rx1 = __shfl(tx1, r), ry1 = __shfl(ty1, r);
                    float rx2 = __shfl(tx2, r), ry2 = __shfl(ty2, r);
                    float ra = __shfl(ta, r);
                    float n_i = -2.f, n_u = 1.f; int ni = 0x7fffffff;
                    for (int i = lane; i < P; i += 64) {
                        if (mask[i >> 5] & (1u << (i & 31))) continue;
                        float4 pr = priors4[i];
                        float px1 = pr.x - pr.z * 0.5f, py1 = pr.y - pr.w * 0.5f;
                        float px2 = pr.x + pr.z * 0.5f, py2 = pr.y + pr.w * 0.5f;
                        float lx = fmaxf(rx1, px1), ly = fmaxf(ry1, py1);
                        float rx = fminf(rx2, px2), ry = fminf(ry2, py2);
                        float w = fmaxf(rx - lx, 0.f), h = fmaxf(ry - ly, 0.f);
                        float inter = w * h;
                        float uni = ra + (px2 - px1) * (py2 - py1) - inter;
                        bool better = inter * n_u > n_i * uni;
                        n_i = better ? inter : n_i; n_u = better ? uni : n_u; ni = better ? i : ni;
                    }
                    float nv = n_i / n_u;
#pragma unroll
                    for (int off = 32; off > 0; off >>= 1) {
                        float ov = __shfl_xor(nv, off);
                        int oi = __shfl_xor(ni, off);
                        if (ov > nv || (ov == nv && oi < ni)) { nv = ov; ni = oi; }
                    }
                    if (lane == r) { rmax = nv; rarg = ni; }
                }
            }
            __syncthreads();
        }
    }
}

// ---------------- K3b: assign loop, parallel last-writer-wins ----------------
__global__ void k_assign(const float* __restrict__ targets,
                         const float* __restrict__ tk_s, const int* __restrict__ tk_i,
                         float* __restrict__ recs, int P, int N) {
    int b = blockIdx.x;
    int tid = threadIdx.x;
    int T = N * KTOP_;  // 160
    __shared__ int sh_p[512];
    __shared__ float sh_s[512];
    __shared__ int sh_c[512];
    if (tid < T) {
        int i = tid / KTOP_, j = tid % KTOP_;
        int p = tk_i[(size_t)(b * N + i) * KTOP_ + j];
        float s = tk_s[(size_t)(b * N + i) * KTOP_ + j];
        const float* base = recs + 4 * ((size_t)b * P + p);
        float bs = base[0];
        int bj = __float_as_int(base[1]) & 0xFFFF;
        float conf1 = (bs < T1_) ? 0.f : targets[(size_t)(b * N + bj) * 5 + 4];
        sh_p[tid] = p; sh_s[tid] = s;
        sh_c[tid] = (conf1 < 1.f && s > 0.f) ? 1 : 0;
    }
    __syncthreads();
    if (tid < T && sh_c[tid]) {
        int p = sh_p[tid];
        bool last = true;
        for (int t2 = tid + 1; t2 < T; t2++) {
            if (sh_c[t2] && sh_p[t2] == p) { last = false; break; }
        }
        if (last) {
            float* base = recs + 4 * ((size_t)b * P + p);
            base[2] = __int_as_float(tid / KTOP_);
            base[3] = sh_s[tid];
        }
    }
}

// ---------------- K4: per-element losses + block partial sums (round-10 proven) ----------------
__global__ void k_loss(const float4* __restrict__ loc4, const float* __restrict__ conf,
                       const float4* __restrict__ priors4, const float* __restrict__ targets,
                       const float4* __restrict__ recs4,
                       double* __restrict__ partials,
                       int P, int N, int C) {
    int b = blockIdx.y;
    int i = blockIdx.x * blockDim.x + threadIdx.x;
    double l1 = 0.0, l2 = 0.0, f1 = 0.0, f2 = 0.0;
    int n1 = 0, n2 = 0;
    if (i < P) {
        size_t bp = (size_t)b * P + i;
        float4 r = recs4[bp];             // one 16B load: {bt_score, btcb, cb_idx2, c_score}
        float bs = r.x;
        int widx = __float_as_int(r.y);
        int bj = widx & 0xFFFF;
        int hadCand = (widx >> 16) & 1;   // == (c_bp_score >= T2)
        float cs = r.w;
        int cj = (cs > 0.f) ? __float_as_int(r.z) : 0;
        float lab1 = targets[(size_t)(b * N + bj) * 5 + 4];
        float conf1 = (bs < T1_) ? 0.f : lab1;
        if ((bs < T1_) && hadCand && (cs < T2_)) conf1 = -1.f;
        float lab2 = targets[(size_t)(b * N + cj) * 5 + 4];
        float conf2 = (cs < T2_) ? -1.f : lab2;
        bool m1 = conf1 > 0.f, m2 = conf2 > 0.f;
        n1 = m1 ? 1 : 0; n2 = m2 ? 1 : 0;

        if (m1 || m2) {   // loc/priors only needed for smooth-l1 of matched priors (~2%)
            float4 pr = priors4[i];
            float pcx = pr.x, pcy = pr.y, pw = pr.z, ph = pr.w;
            float4 lc = loc4[bp];
            float p0 = lc.x, p1 = lc.y, p2 = lc.z, p3 = lc.w;
            if (m1) {
                const float* tb = &targets[(size_t)(b * N + bj) * 5];
                float gx = ((tb[0] + tb[2]) * 0.5f - pcx) / (VAR0_ * pw);
                float gy = ((tb[1] + tb[3]) * 0.5f - pcy) / (VAR0_ * ph);
                float gw = logf((tb[2] - tb[0]) / pw) / VAR1_;
                float gh = logf((tb[3] - tb[1]) / ph) / VAR1_;
                l1 = (double)(sl1(p0 - gx) + sl1(p1 - gy) + sl1(p2 - gw) + sl1(p3 - gh));
            }
            if (m2) {
                const float* tb = &targets[(size_t)(b * N + cj) * 5];
                float gx = ((tb[0] + tb[2]) * 0.5f - pcx) / (VAR0_ * pw);
                float gy = ((tb[1] + tb[3]) * 0.5f - pcy) / (VAR0_ * ph);
                float gw = logf((tb[2] - tb[0]) / pw) / VAR1_;
                float gh = logf((tb[3] - tb[1]) / ph) / VAR1_;
                l2 = (double)(sl1(p0 - gx) + sl1(p1 - gy) + sl1(p2 - gw) + sl1(p3 - gh));
            }
        }
        float x0, x1v;
        if (C == 2) {
            float2 cv2 = ((const float2*)conf)[bp];
            x0 = cv2.x; x1v = cv2.y;
        } else {
            x0 = conf[bp * C + 0]; x1v = conf[bp * C + 1];
        }
        {   // focal 1
            float t = fmaxf(conf1, 0.f);
            float keep = (conf1 >= 0.f) ? 1.f : 0.f;
            float x = (t >= 1.f) ? x1v : x0;
            float ce = fmaxf(x, 0.f) - x * t + log1pf(expf(-fabsf(x)));
            float a = t * ALPHA_ + (1.f - t) * (1.f - ALPHA_);
            float pr_ = 1.f / (1.f + expf(-x));
            float pt = (t == 1.f) ? pr_ : (1.f - pr_);
            float om = 1.f - pt;
            f1 = (double)(a * om * om * ce * keep);
        }
        {   // focal 2 (iou-weighted)
            float t = fmaxf(conf2, 0.f);
            float keep = (conf2 >= 0.f) ? 1.f : 0.f;
            float x = (t >= 1.f) ? x1v : x0;
            float ce = fmaxf(x, 0.f) - x * t + log1pf(expf(-fabsf(x)));
            float a = cs * (t * ALPHA_ + (1.f - t) * (1.f - ALPHA_));
            float pr_ = 1.f / (1.f + expf(-x));
            float pt = (t == 1.f) ? pr_ : (1.f - pr_);
            float om = 1.f - pt;
            f2 = (double)(a * om * om * ce * keep);
        }
    }
    int tid = threadIdx.x;
    int lane = tid & 63, wid = tid >> 6;
#pragma unroll
    for (int off = 32; off > 0; off >>= 1) {
        l1 += __shfl_xor(l1, off);
        l2 += __shfl_xor(l2, off);
        f1 += __shfl_xor(f1, off);
        f2 += __shfl_xor(f2, off);
        n1 += __shfl_xor(n1, off);
        n2 += __shfl_xor(n2, off);
    }
    __shared__ double swd[BS / 64][4];
    __shared__ int swn[BS / 64][2];
    if (lane == 0) {
        swd[wid][0] = l1; swd[wid][1] = l2; swd[wid][2] = f1; swd[wid][3] = f2;
        swn[wid][0] = n1; swn[wid][1] = n2;
    }
    __syncthreads();
    if (tid == 0) {
        double a0 = 0, a1 = 0, a2 = 0, a3 = 0; int b0 = 0, b1 = 0;
        for (int wv = 0; wv < BS / 64; wv++) {
            a0 += swd[wv][0]; a1 += swd[wv][1]; a2 += swd[wv][2]; a3 += swd[wv][3];
            b0 += swn[wv][0]; b1 += swn[wv][1];
        }
        int blk = blockIdx.y * gridDim.x + blockIdx.x;
        partials[(size_t)blk * 6 + 0] = a0;
        partials[(size_t)blk * 6 + 1] = a1;
        partials[(size_t)blk * 6 + 2] = a2;
        partials[(size_t)blk * 6 + 3] = a3;
        partials[(size_t)blk * 6 + 4] = (double)b0;
        partials[(size_t)blk * 6 + 5] = (double)b1;
    }
}

// ---------------- K5: final reduction + loss assembly (round-10 proven) ----------------
__global__ void k_final(const double* __restrict__ partials, int nPart, float* __restrict__ out) {
    int tid = threadIdx.x;
    double a[6] = {0, 0, 0, 0, 0, 0};
    for (int k = tid; k < nPart; k += BS) {
#pragma unroll
        for (int j = 0; j < 6; j++) a[j] += partials[(size_t)k * 6 + j];
    }
    __shared__ double sd[BS * 6];
#pragma unroll
    for (int j = 0; j < 6; j++) sd[tid * 6 + j] = a[j];
    __syncthreads();
    for (int s = BS / 2; s > 0; s >>= 1) {
        if (tid < s) {
#pragma unroll
            for (int j = 0; j < 6; j++) sd[tid * 6 + j] += sd[(tid + s) * 6 + j];
        }
        __syncthreads();
    }
    if (tid == 0) {
        double L1 = sd[0], L2 = sd[1], F1 = sd[2], F2 = sd[3], N1 = sd[4], N2 = sd[5];
        double l1v = L1 / fmax(N1, 1.0), l2v = L2 / fmax(N2, 1.0);
        double f1v = F1 / fmax(N1, 1.0), f2v = F2 / fmax(N2, 1.0);
        double locl = (N1 > 0 ? l1v : 0.0) + (N2 > 0 ? l2v : 0.0);
        double clsl = (N1 > 0 ? f1v : 0.0) + (N2 > 0 ? f2v : 0.0);
        if (N1 == 0 && N2 == 0) { locl = 1e-4; clsl = 1e-4; }
        out[0] = (float)locl;
        out[1] = (float)clsl;
    }
}

extern "C" void kernel_launch(void* const* d_in, const int* in_sizes, int n_in,
                              void* d_out, int out_size, void* d_ws, size_t ws_size,
                              hipStream_t stream) {
    const float* targets = (const float*)d_in[3];
    const float* conf = (const float*)d_in[1];
    const float4* loc4 = (const float4*)d_in[0];
    const float4* priors4 = (const float4*)d_in[2];

    int P = in_sizes[2] / 4;
    int B = in_sizes[0] / (P * 4);
    int N = in_sizes[3] / (B * 5);
    int C = in_sizes[1] / (B * P);
    const int CAP = 2048;
    size_t BP = (size_t)B * P;

    unsigned char* ws = (unsigned char*)d_ws;
    size_t off = 0;
    auto alloc = [&](size_t bytes) { size_t cur = off; off += (bytes + 255) & ~(size_t)255; return cur; };
    float* recs = (float*)(ws + alloc(BP * 16));      // packed {bt_score, btcb, cb_idx2, c_score}
    float* part_max = (float*)(ws + alloc((size_t)B * N * NSPLIT * 4));
    int* part_arg = (int*)(ws + alloc((size_t)B * N * NSPLIT * 4));
    float* tk_s = (float*)(ws + alloc((size_t)B * N * KTOP_ * 4));
    int* tk_i = (int*)(ws + alloc((size_t)B * N * KTOP_ * 4));
    float* cand_v = (float*)(ws + alloc((size_t)B * N * CAP * 4));
    int* cand_i = (int*)(ws + alloc((size_t)B * N * CAP * 4));
    int* cand_cnt = (int*)(ws + alloc((size_t)B * N * 4));
    int bx = (P + BS - 1) / BS;
    double* partials = (double*)(ws + alloc((size_t)bx * B * 6 * 8));
    float* out = (float*)d_out;

    hipMemsetAsync(cand_cnt, 0, (size_t)B * N * 4, stream);

    int bx4 = (P + BSK * ILP - 1) / (BSK * ILP);
    k_per_prior<<<dim3(bx4, B), BSK, 0, stream>>>(loc4, priors4, targets, (float4*)recs,
                                                  cand_v, cand_i, cand_cnt, P, N, CAP);
    int ngroup = (N + 3) / 4;
    k_row_max_part<<<dim3(NSPLIT, B, ngroup), BS, 0, stream>>>(priors4, targets,
                                                               part_max, part_arg, P, N);
    int maskWords = (P + 31) / 32;
    size_t shmem = (size_t)maskWords * 4;
    k_fat2<<<dim3(N + 1, B), BS, shmem, stream>>>(loc4, priors4, targets,
                                                  cand_v, cand_i, cand_cnt, tk_s, tk_i,
                                                  part_max, part_arg, recs, P, N, CAP);
    k_assign<<<dim3(B), BS, 0, stream>>>(targets, tk_s, tk_i, recs, P, N);
    k_loss<<<dim3(bx, B), BS, 0, stream>>>(loc4, conf, priors4, targets, (const float4*)recs,
                                           partials, P, N, C);
    k_final<<<1, BS, 0, stream>>>(partials, bx * B, out);
}